// Round 1
// baseline (228.937 us; speedup 1.0000x reference)
//
#include <hip/hip_runtime.h>
#include <math.h>

#define NN 50000
#define NE 800000
#define IN_CH 64
#define HEADS 8
#define OC 16
#define HID 128
#define NG 500
#define GB2 ((NN + 63) / 64)        // 782 MFMA-GEMM blocks (64-node tiles)
#define SB 3125                     // scatter blocks: 3125*256 == NE exactly, 1 edge/thread
#define SLOT 64                     // padded-CSR slot per node (max deg ~35)
#define XP 72                       // xb LDS pitch (bf16)
#define WP 72                       // wt LDS pitch (bf16)

typedef float v2f __attribute__((ext_vector_type(2)));
typedef __attribute__((ext_vector_type(8))) short frag8;   // 8 bf16 (4 VGPRs)
typedef __attribute__((ext_vector_type(4))) float f32x4;   // MFMA C/D

// round-to-nearest-even f32 -> bf16 (as ushort in low bits)
__device__ __forceinline__ unsigned bf16rn(float f) {
    unsigned u = __float_as_uint(f);
    return (u + 0x7fffu + ((u >> 16) & 1u)) >> 16;
}

// Sum across the 8-lane head group using DPP (VALU pipe, no LDS).
__device__ __forceinline__ float dpp8_sum(float x) {
    int t;
    t = __builtin_amdgcn_update_dpp(0, __float_as_int(x), 0xB1, 0xF, 0xF, true);  // quad_perm [1,0,3,2]
    x += __int_as_float(t);
    t = __builtin_amdgcn_update_dpp(0, __float_as_int(x), 0x4E, 0xF, 0xF, true);  // quad_perm [2,3,0,1]
    x += __int_as_float(t);
    t = __builtin_amdgcn_update_dpp(0, __float_as_int(x), 0x141, 0xF, 0xF, true); // row_half_mirror
    x += __int_as_float(t);
    return x;
}

// ---------------- fused: MFMA GEMM (blocks <GB2) + padded scatter ----------
// R19: padded CSR kills the deg/scan chain. R20: ALL gemm outputs bf16.
// R21 (this round): col_src as ushort + CACHEABLE stores (no NT). The NT 4B
// stores generated ~50 MB of HBM write traffic (800K x 64B lines, no L2
// write-combining). Cacheable ushort stores let L2's byte-mask writeback
// merge the ~16 stores/node into ~1 line => col_src HBM writes ~50 -> ~6 MB.
// Scatter is 1 edge/thread (SB*256 == NE): full 64-lane atomic batches in
// flight, no sequential per-thread atomic->store chains.
__global__ __launch_bounds__(256) void k_work(
    const float* __restrict__ x, const int* __restrict__ ei,
    const float* __restrict__ Wl, const float* __restrict__ bl,
    const float* __restrict__ Wr, const float* __restrict__ br,
    const float* __restrict__ Wres,
    unsigned short* __restrict__ xlh, unsigned short* __restrict__ xrh,
    unsigned short* __restrict__ xresh,
    int* __restrict__ cnt, unsigned short* __restrict__ col_src)
{
    const int tid = threadIdx.x;

    if (blockIdx.x >= GB2) {           // scatter-only block (no barriers)
        const int e = (blockIdx.x - GB2) * 256 + tid;
        if (e < NE) {
            const int s = ei[e];
            const int d = ei[NE + e];
            if ((unsigned)d < NN) {                    // defensive
                const int pos = atomicAdd(&cnt[d], 1);
                if ((unsigned)pos < SLOT)
                    col_src[(size_t)d * SLOT + pos] = (unsigned short)s;
            }
        }
        return;
    }

    __shared__ short xb[64 * XP];      // [node][k] bf16
    __shared__ short wt[128 * WP];     // [col][k] bf16 (W transposed)
    const int n0 = blockIdx.x * 64;

    // stage xb: 64 nodes x 64 k, fp32->bf16
#pragma unroll
    for (int i = 0; i < 4; ++i) {
        const int idx = i * 256 + tid;           // 0..1023 float4s
        const int r = idx >> 4;
        const int j4 = idx & 15;
        float4 v = make_float4(0.f, 0.f, 0.f, 0.f);
        if (n0 + r < NN) v = *(const float4*)(x + (size_t)(n0 + r) * IN_CH + j4 * 4);
        uint2 pk;
        pk.x = bf16rn(v.x) | (bf16rn(v.y) << 16);
        pk.y = bf16rn(v.z) | (bf16rn(v.w) << 16);
        *(uint2*)(xb + r * XP + j4 * 4) = pk;
    }

    const int wv = tid >> 6;           // wave 0..3 -> node subtile
    const int lane = tid & 63;
    const int quad = lane >> 4;
    const int mr = lane & 15;
    const int m0 = wv * 16;

    for (int mtx = 0; mtx < 3; ++mtx) {
        const float* __restrict__ W = (mtx == 0) ? Wl : (mtx == 1) ? Wr : Wres;
        unsigned short* __restrict__ outp = (mtx == 0) ? xlh : (mtx == 1) ? xrh : xresh;

        __syncthreads();   // xb staged (mtx=0) / previous wt consumed (mtx>0)
#pragma unroll
        for (int i = 0; i < 16; ++i) {
            const int idx = i * 256 + tid;       // 0..4095: kp 0..31, c 0..127
            const int kp = idx >> 7;
            const int c = idx & 127;
            const float w0 = W[(2 * kp) * HID + c];
            const float w1 = W[(2 * kp + 1) * HID + c];
            *(unsigned*)(wt + c * WP + 2 * kp) = bf16rn(w0) | (bf16rn(w1) << 16);
        }
        __syncthreads();

        const frag8 a0 = *(const frag8*)(xb + (m0 + mr) * XP + quad * 8);
        const frag8 a1 = *(const frag8*)(xb + (m0 + mr) * XP + 32 + quad * 8);

#pragma unroll
        for (int nt = 0; nt < 8; ++nt) {
            const int c = nt * 16 + mr;          // this lane's global column
            const frag8 b0 = *(const frag8*)(wt + c * WP + quad * 8);
            const frag8 b1 = *(const frag8*)(wt + c * WP + 32 + quad * 8);
            f32x4 acc = {0.f, 0.f, 0.f, 0.f};
            acc = __builtin_amdgcn_mfma_f32_16x16x32_bf16(a0, b0, acc, 0, 0, 0);
            acc = __builtin_amdgcn_mfma_f32_16x16x32_bf16(a1, b1, acc, 0, 0, 0);

            const float bv = (mtx == 0) ? bl[c] : (mtx == 1) ? br[c] : 0.f;
            const int node_base = n0 + m0 + quad * 4;
#pragma unroll
            for (int r = 0; r < 4; ++r) {
                const int node = node_base + r;
                if (node < NN)
                    outp[(size_t)node * HID + c] = (unsigned short)bf16rn(acc[r] + bv);
            }
        }
    }
}

// ---- Fused attention: single-pass softmax-aggregate, all-bf16 payload ------
// Padded CSR: beg = n*SLOT, cnt[n] <= SLOT -> exactly one 64-wide block.
__global__ __launch_bounds__(256) void k_agg(
    const unsigned short* __restrict__ xlh, const unsigned short* __restrict__ xrh,
    const unsigned short* __restrict__ xresh,
    const int* __restrict__ cnt, const unsigned short* __restrict__ col_src,
    const float* __restrict__ att, const float* __restrict__ bias,
    float* __restrict__ hfeat)
{
    const int lane = threadIdx.x & 63;
    const int wid = __builtin_amdgcn_readfirstlane((blockIdx.x * blockDim.x + threadIdx.x) >> 6);
    const int nw = (gridDim.x * blockDim.x) >> 6;
    const int c0 = lane * 2;
    const int hh = lane >> 3;
    const int ci = (lane & 7) * 2;
    v2f a2;  a2.x = att[hh * OC + ci];  a2.y = att[hh * OC + ci + 1];
    v2f b2;  b2.x = bias[c0];           b2.y = bias[c0 + 1];

    for (int n = wid; n < NN; n += nw) {
        int cn = cnt[n];                                  // uniform s_load
        cn = min(max(cn, 0), SLOT);                       // defensive
        const size_t beg = (size_t)n * SLOT;
        const unsigned vvr = *((const unsigned*)(xrh + (size_t)n * HID) + lane);
        v2f xrn2;
        xrn2.x = __uint_as_float(vvr << 16);
        xrn2.y = __uint_as_float(vvr & 0xffff0000u);
        const unsigned vvn = *((const unsigned*)(xlh + (size_t)n * HID) + lane);
        v2f xln2;
        xln2.x = __uint_as_float(vvn << 16);
        xln2.y = __uint_as_float(vvn & 0xffff0000u);
        v2f s2 = xln2 + xrn2;
        v2f l2 = __builtin_elementwise_max(s2, s2 * 0.2f);
        v2f d2 = l2 * a2;
        const float qs = dpp8_sum(d2.x + d2.y);

        float den = __expf(qs);                 // self-loop term
        v2f acc2 = den * xln2;

        int sidx = 0;
        if (lane < cn) sidx = (int)col_src[beg + lane];
        if ((unsigned)sidx >= NN) sidx = 0;               // bound all gathers
        int j = 0;
        // full batches: no per-slot predication
        for (; j + 8 <= cn; j += 8) {
            int s[8]; unsigned vv[8];
#pragma unroll
            for (int u = 0; u < 8; ++u) s[u] = __builtin_amdgcn_readlane(sidx, j + u);
#pragma unroll
            for (int u = 0; u < 8; ++u)
                vv[u] = *((const unsigned*)(xlh + (size_t)s[u] * HID) + lane);
#pragma unroll
            for (int u = 0; u < 8; ++u) {
                v2f xv;
                xv.x = __uint_as_float(vv[u] << 16);
                xv.y = __uint_as_float(vv[u] & 0xffff0000u);
                v2f t2 = xv + xrn2;
                v2f e2 = __builtin_elementwise_max(t2, t2 * 0.2f);
                v2f p2 = e2 * a2;
                const float q = dpp8_sum(p2.x + p2.y);
                const float w = __expf(q);
                den += w;
                acc2 += w * xv;
            }
        }
        // tail batch (predicated)
        if (j < cn) {
            int s[8]; unsigned vv[8];
#pragma unroll
            for (int u = 0; u < 8; ++u) s[u] = __builtin_amdgcn_readlane(sidx, j + u);
#pragma unroll
            for (int u = 0; u < 8; ++u)
                vv[u] = *((const unsigned*)(xlh + (size_t)s[u] * HID) + lane);
#pragma unroll
            for (int u = 0; u < 8; ++u) {
                v2f xv;
                xv.x = __uint_as_float(vv[u] << 16);
                xv.y = __uint_as_float(vv[u] & 0xffff0000u);
                v2f t2 = xv + xrn2;
                v2f e2 = __builtin_elementwise_max(t2, t2 * 0.2f);
                v2f p2 = e2 * a2;
                const float q = dpp8_sum(p2.x + p2.y);
                if (j + u < cn) {
                    const float w = __expf(q);
                    den += w;
                    acc2 += w * xv;
                }
            }
        }

        const unsigned vvs = *((const unsigned*)(xresh + (size_t)n * HID) + lane);
        v2f xrs2;
        xrs2.x = __uint_as_float(vvs << 16);
        xrs2.y = __uint_as_float(vvs & 0xffff0000u);
        const float inv = 1.f / den;
        v2f t = acc2 * inv + xrs2 + b2;
        float2 st; st.x = t.x; st.y = t.y;
        *(float2*)(hfeat + (size_t)n * HID + c0) = st;
    }
}

// ---- Fused tail: per-graph {Wlin+ELU pool} + MLP ---------------------------
__global__ __launch_bounds__(256) void k_tail(
    const float* __restrict__ hfeat, const int* __restrict__ batch,
    const float* __restrict__ Wlin, const float* __restrict__ blin,
    const float* __restrict__ W1, const float* __restrict__ b1,
    const float* __restrict__ W2, const float* __restrict__ b2,
    const float* __restrict__ W3, const float* __restrict__ b3,
    float* __restrict__ out)
{
    __shared__ float sWlin[HID * 16];
    __shared__ float sblin[16];
    __shared__ float sW1[256], sb1[16], sW2[512], sb2[32], sW3[160], sb3[5];
    __shared__ float red[256][17];
    __shared__ float sg[16], sv1[16], sv2[32];
    const int g = blockIdx.x;
    const int tid = threadIdx.x;

    for (int i = tid; i < HID * 16; i += 256) sWlin[i] = Wlin[i];
    if (tid < 16)  sblin[tid] = blin[tid];
    if (tid < 256) sW1[tid] = W1[tid];
    for (int i = tid; i < 512; i += 256) sW2[i] = W2[i];
    if (tid < 160) sW3[tid] = W3[tid];
    if (tid < 16)  sb1[tid] = b1[tid];
    if (tid < 32)  sb2[tid] = b2[tid];
    if (tid < 5)   sb3[tid] = b3[tid];
    __syncthreads();

    int lo = 0, hi = NN;
    while (lo < hi) { int mid = (lo + hi) >> 1; if (batch[mid] < g) lo = mid + 1; else hi = mid; }
    int lo2 = lo, hi2 = NN;
    while (lo2 < hi2) { int mid = (lo2 + hi2) >> 1; if (batch[mid] < g + 1) lo2 = mid + 1; else hi2 = mid; }
    const int nbeg = lo, nend = lo2;

    float sum16[16];
#pragma unroll
    for (int j = 0; j < 16; ++j) sum16[j] = 0.f;

    for (int n = nbeg + tid; n < nend; n += 256) {
        float acc[16];
#pragma unroll
        for (int j = 0; j < 16; ++j) acc[j] = sblin[j];
        const float4* hrow = (const float4*)(hfeat + (size_t)n * HID);
#pragma unroll 8
        for (int kc = 0; kc < 32; ++kc) {
            const float4 v = hrow[kc];
#pragma unroll
            for (int j = 0; j < 16; ++j) {
                acc[j] += v.x * sWlin[(kc * 4 + 0) * 16 + j] + v.y * sWlin[(kc * 4 + 1) * 16 + j]
                        + v.z * sWlin[(kc * 4 + 2) * 16 + j] + v.w * sWlin[(kc * 4 + 3) * 16 + j];
            }
        }
#pragma unroll
        for (int j = 0; j < 16; ++j) {
            float o = acc[j];
            o = o > 0.f ? o : __expf(o) - 1.f;
            sum16[j] += o;
        }
    }

#pragma unroll
    for (int j = 0; j < 16; ++j) red[tid][j] = sum16[j];
    __syncthreads();
    for (int s = 128; s > 0; s >>= 1) {
        if (tid < s) {
#pragma unroll
            for (int j = 0; j < 16; ++j) red[tid][j] += red[tid + s][j];
        }
        __syncthreads();
    }

    if (tid < 16) sg[tid] = red[0][tid] / fmaxf((float)(nend - nbeg), 1.f);
    __syncthreads();
    if (tid < 16) {
        float s = sb1[tid];
#pragma unroll
        for (int c = 0; c < 16; ++c) s += sg[c] * sW1[c * 16 + tid];
        sv1[tid] = fmaxf(s, 0.f);
    }
    __syncthreads();
    if (tid < 32) {
        float s = sb2[tid];
#pragma unroll
        for (int c = 0; c < 16; ++c) s += sv1[c] * sW2[c * 32 + tid];
        sv2[tid] = fmaxf(s, 0.f);
    }
    __syncthreads();
    if (tid < 5) {
        float s = sb3[tid];
#pragma unroll
        for (int c = 0; c < 32; ++c) s += sv2[c] * sW3[c * 5 + tid];
        out[g * 5 + tid] = s;
    }
}

extern "C" void kernel_launch(void* const* d_in, const int* in_sizes, int n_in,
                              void* d_out, int out_size, void* d_ws, size_t ws_size,
                              hipStream_t stream)
{
    const float* x    = (const float*)d_in[0];
    const int*   ei   = (const int*)d_in[1];
    const int*   batch= (const int*)d_in[2];
    const float* Wl   = (const float*)d_in[3];
    const float* bl   = (const float*)d_in[4];
    const float* Wr   = (const float*)d_in[5];
    const float* br   = (const float*)d_in[6];
    const float* att  = (const float*)d_in[7];
    const float* Wres = (const float*)d_in[8];
    const float* bias = (const float*)d_in[9];
    const float* Wlin = (const float*)d_in[10];
    const float* blin = (const float*)d_in[11];
    const float* W1   = (const float*)d_in[12];
    const float* b1   = (const float*)d_in[13];
    const float* W2   = (const float*)d_in[14];
    const float* b2   = (const float*)d_in[15];
    const float* W3   = (const float*)d_in[16];
    const float* b3   = (const float*)d_in[17];
    float* out = (float*)d_out;

    uintptr_t p = (uintptr_t)d_ws;
    unsigned short* xlh   = (unsigned short*)p; p += (size_t)NN * HID * 2;
    unsigned short* xrh   = (unsigned short*)p; p += (size_t)NN * HID * 2;
    unsigned short* xresh = (unsigned short*)p; p += (size_t)NN * HID * 2;
    p = (p + 15) & ~(uintptr_t)15;
    float* hfeat  = (float*)p; p += (size_t)NN * HID * 4;
    int* cnt      = (int*)p;   p += (size_t)NN * 4;
    unsigned short* col_src = (unsigned short*)p; p += (size_t)NN * SLOT * 2;

    hipMemsetAsync(cnt, 0, (size_t)NN * sizeof(int), stream);
    k_work<<<GB2 + SB, 256, 0, stream>>>(x, ei, Wl, bl, Wr, br, Wres,
                                         xlh, xrh, xresh, cnt, col_src);
    k_agg<<<2048, 256, 0, stream>>>(xlh, xrh, xresh, cnt, col_src, att, bias, hfeat);
    k_tail<<<NG, 256, 0, stream>>>(hfeat, batch, Wlin, blin,
                                   W1, b1, W2, b2, W3, b3, out);
}

// Round 2
// 218.995 us; speedup vs baseline: 1.0454x; 1.0454x over previous
//
#include <hip/hip_runtime.h>
#include <math.h>

#define NN 50000
#define NE 800000
#define IN_CH 64
#define HEADS 8
#define OC 16
#define HID 128
#define NG 500
#define GB2 ((NN + 63) / 64)        // 782 MFMA-GEMM blocks (64-node tiles)
#define SB 3125                     // scatter blocks: 3125*256 == NE exactly, 1 edge/thread
#define NGRP 8                      // XCD-private CSR groups
#define SLOTG 8                     // slots per node per group (deg/XCD ~ Po(2))
#define OVS 64                      // overflow slots per node (device-scope path)
#define XP 72                       // xb LDS pitch (bf16)
#define WP 72                       // wt LDS pitch (bf16)

typedef float v2f __attribute__((ext_vector_type(2)));
typedef __attribute__((ext_vector_type(8))) short frag8;   // 8 bf16 (4 VGPRs)
typedef __attribute__((ext_vector_type(4))) float f32x4;   // MFMA C/D

// round-to-nearest-even f32 -> bf16 (as ushort in low bits)
__device__ __forceinline__ unsigned bf16rn(float f) {
    unsigned u = __float_as_uint(f);
    return (u + 0x7fffu + ((u >> 16) & 1u)) >> 16;
}

// Sum across the 8-lane head group using DPP (VALU pipe, no LDS).
__device__ __forceinline__ float dpp8_sum(float x) {
    int t;
    t = __builtin_amdgcn_update_dpp(0, __float_as_int(x), 0xB1, 0xF, 0xF, true);  // quad_perm [1,0,3,2]
    x += __int_as_float(t);
    t = __builtin_amdgcn_update_dpp(0, __float_as_int(x), 0x4E, 0xF, 0xF, true);  // quad_perm [2,3,0,1]
    x += __int_as_float(t);
    t = __builtin_amdgcn_update_dpp(0, __float_as_int(x), 0x141, 0xF, 0xF, true); // row_half_mirror
    x += __int_as_float(t);
    return x;
}

// ---------------- fused: MFMA GEMM (blocks <GB2) + XCD-private scatter -----
// R22: the 800K device-scope atomicAdds were ~51 MB (800K x 64B) of fabric
// RMW traffic (R21 post-mortem: WRITE residual == edges x 64B, insensitive
// to store width/NT). Fix: XCD-private counters + slots, addressed by the
// REAL XCC_ID (s_getreg, m09). Workgroup-scope atomic => global_atomic_add
// without SC1 => executes in this XCD's L2; same-XCD cross-block atomicity
// is physical (single TCC per address per XCD). Group g lines are written
// only by XCD g => counters stay L2-resident, col_src lines write-combine.
// Overflow (group full, ~100 edges expected; any dispatch skew) falls back
// to a device-scope atomic into a 64-slot spill group => always correct.
__global__ __launch_bounds__(256) void k_work(
    const float* __restrict__ x, const int* __restrict__ ei,
    const float* __restrict__ Wl, const float* __restrict__ bl,
    const float* __restrict__ Wr, const float* __restrict__ br,
    const float* __restrict__ Wres,
    unsigned short* __restrict__ xlh, unsigned short* __restrict__ xrh,
    unsigned short* __restrict__ xresh,
    int* __restrict__ cnt,                 // [NGRP+1][NN]
    unsigned short* __restrict__ col_src,  // [NGRP][NN][SLOTG]
    unsigned short* __restrict__ ov)       // [NN][OVS]
{
    const int tid = threadIdx.x;

    if (blockIdx.x >= GB2) {           // scatter-only block (no barriers)
        const int e = (blockIdx.x - GB2) * 256 + tid;
        if (e < NE) {
            const int s = ei[e];
            const int d = ei[NE + e];
            if ((unsigned)d < NN) {                    // defensive
                int xcc;
                asm volatile("s_getreg_b32 %0, hwreg(HW_REG_XCC_ID)" : "=s"(xcc));
                const int g = xcc & (NGRP - 1);
                const int pos = __hip_atomic_fetch_add(&cnt[(size_t)g * NN + d], 1,
                                                       __ATOMIC_RELAXED,
                                                       __HIP_MEMORY_SCOPE_WORKGROUP);
                if (pos < SLOTG) {
                    col_src[((size_t)g * NN + d) * SLOTG + pos] = (unsigned short)s;
                } else {
                    const int po = atomicAdd(&cnt[(size_t)NGRP * NN + d], 1);  // device scope
                    if (po < OVS)
                        ov[(size_t)d * OVS + po] = (unsigned short)s;
                }
            }
        }
        return;
    }

    __shared__ short xb[64 * XP];      // [node][k] bf16
    __shared__ short wt[128 * WP];     // [col][k] bf16 (W transposed)
    const int n0 = blockIdx.x * 64;

    // stage xb: 64 nodes x 64 k, fp32->bf16
#pragma unroll
    for (int i = 0; i < 4; ++i) {
        const int idx = i * 256 + tid;           // 0..1023 float4s
        const int r = idx >> 4;
        const int j4 = idx & 15;
        float4 v = make_float4(0.f, 0.f, 0.f, 0.f);
        if (n0 + r < NN) v = *(const float4*)(x + (size_t)(n0 + r) * IN_CH + j4 * 4);
        uint2 pk;
        pk.x = bf16rn(v.x) | (bf16rn(v.y) << 16);
        pk.y = bf16rn(v.z) | (bf16rn(v.w) << 16);
        *(uint2*)(xb + r * XP + j4 * 4) = pk;
    }

    const int wv = tid >> 6;           // wave 0..3 -> node subtile
    const int lane = tid & 63;
    const int quad = lane >> 4;
    const int mr = lane & 15;
    const int m0 = wv * 16;

    for (int mtx = 0; mtx < 3; ++mtx) {
        const float* __restrict__ W = (mtx == 0) ? Wl : (mtx == 1) ? Wr : Wres;
        unsigned short* __restrict__ outp = (mtx == 0) ? xlh : (mtx == 1) ? xrh : xresh;

        __syncthreads();   // xb staged (mtx=0) / previous wt consumed (mtx>0)
#pragma unroll
        for (int i = 0; i < 16; ++i) {
            const int idx = i * 256 + tid;       // 0..4095: kp 0..31, c 0..127
            const int kp = idx >> 7;
            const int c = idx & 127;
            const float w0 = W[(2 * kp) * HID + c];
            const float w1 = W[(2 * kp + 1) * HID + c];
            *(unsigned*)(wt + c * WP + 2 * kp) = bf16rn(w0) | (bf16rn(w1) << 16);
        }
        __syncthreads();

        const frag8 a0 = *(const frag8*)(xb + (m0 + mr) * XP + quad * 8);
        const frag8 a1 = *(const frag8*)(xb + (m0 + mr) * XP + 32 + quad * 8);

#pragma unroll
        for (int nt = 0; nt < 8; ++nt) {
            const int c = nt * 16 + mr;          // this lane's global column
            const frag8 b0 = *(const frag8*)(wt + c * WP + quad * 8);
            const frag8 b1 = *(const frag8*)(wt + c * WP + 32 + quad * 8);
            f32x4 acc = {0.f, 0.f, 0.f, 0.f};
            acc = __builtin_amdgcn_mfma_f32_16x16x32_bf16(a0, b0, acc, 0, 0, 0);
            acc = __builtin_amdgcn_mfma_f32_16x16x32_bf16(a1, b1, acc, 0, 0, 0);

            const float bv = (mtx == 0) ? bl[c] : (mtx == 1) ? br[c] : 0.f;
            const int node_base = n0 + m0 + quad * 4;
#pragma unroll
            for (int r = 0; r < 4; ++r) {
                const int node = node_base + r;
                if (node < NN)
                    outp[(size_t)node * HID + c] = (unsigned short)bf16rn(acc[r] + bv);
            }
        }
    }
}

// ---- Fused attention: single-pass softmax-aggregate, all-bf16 payload ------
// Grouped CSR: lane -> (g = lane>>3, i = lane&7) reads its group slot;
// ballot + ds_permute compacts valid srcs to lanes [0, cn). Overflow edges
// (rare) processed one-at-a-time broadcast-style.
__global__ __launch_bounds__(256) void k_agg(
    const unsigned short* __restrict__ xlh, const unsigned short* __restrict__ xrh,
    const unsigned short* __restrict__ xresh,
    const int* __restrict__ cnt, const unsigned short* __restrict__ col_src,
    const unsigned short* __restrict__ ov,
    const float* __restrict__ att, const float* __restrict__ bias,
    float* __restrict__ hfeat)
{
    const int lane = threadIdx.x & 63;
    const int wid = __builtin_amdgcn_readfirstlane((blockIdx.x * blockDim.x + threadIdx.x) >> 6);
    const int nw = (gridDim.x * blockDim.x) >> 6;
    const int c0 = lane * 2;
    const int hh = lane >> 3;
    const int ci = (lane & 7) * 2;
    const int grp = lane >> 3;          // this lane's CSR group
    const int gsl = lane & 7;           // slot within group
    v2f a2;  a2.x = att[hh * OC + ci];  a2.y = att[hh * OC + ci + 1];
    v2f b2;  b2.x = bias[c0];           b2.y = bias[c0 + 1];

    for (int n = wid; n < NN; n += nw) {
        int cg = cnt[(size_t)grp * NN + n];
        cg = min(max(cg, 0), SLOTG);                      // defensive
        int cov = cnt[(size_t)NGRP * NN + n];
        cov = min(max(cov, 0), OVS);
        const bool valid = gsl < cg;
        const unsigned long long mv = __ballot(valid);
        const int cn = __popcll(mv);
        int slot_s = 0;
        if (valid) slot_s = (int)col_src[((size_t)grp * NN + n) * SLOTG + gsl];
        // compact valid srcs to lanes [0, cn): unique destinations
        const int pv = __popcll(mv & ((1ull << lane) - 1ull));
        const int dst = valid ? pv : (cn + (lane - pv));
        int sidx = __builtin_amdgcn_ds_permute(dst << 2, slot_s);
        if ((unsigned)sidx >= NN) sidx = 0;               // bound all gathers

        const unsigned vvr = *((const unsigned*)(xrh + (size_t)n * HID) + lane);
        v2f xrn2;
        xrn2.x = __uint_as_float(vvr << 16);
        xrn2.y = __uint_as_float(vvr & 0xffff0000u);
        const unsigned vvn = *((const unsigned*)(xlh + (size_t)n * HID) + lane);
        v2f xln2;
        xln2.x = __uint_as_float(vvn << 16);
        xln2.y = __uint_as_float(vvn & 0xffff0000u);
        v2f s2 = xln2 + xrn2;
        v2f l2 = __builtin_elementwise_max(s2, s2 * 0.2f);
        v2f d2 = l2 * a2;
        const float qs = dpp8_sum(d2.x + d2.y);

        float den = __expf(qs);                 // self-loop term
        v2f acc2 = den * xln2;

        int j = 0;
        // full batches: no per-slot predication
        for (; j + 8 <= cn; j += 8) {
            int s[8]; unsigned vv[8];
#pragma unroll
            for (int u = 0; u < 8; ++u) s[u] = __builtin_amdgcn_readlane(sidx, j + u);
#pragma unroll
            for (int u = 0; u < 8; ++u)
                vv[u] = *((const unsigned*)(xlh + (size_t)s[u] * HID) + lane);
#pragma unroll
            for (int u = 0; u < 8; ++u) {
                v2f xv;
                xv.x = __uint_as_float(vv[u] << 16);
                xv.y = __uint_as_float(vv[u] & 0xffff0000u);
                v2f t2 = xv + xrn2;
                v2f e2 = __builtin_elementwise_max(t2, t2 * 0.2f);
                v2f p2 = e2 * a2;
                const float q = dpp8_sum(p2.x + p2.y);
                const float w = __expf(q);
                den += w;
                acc2 += w * xv;
            }
        }
        // tail batch (predicated)
        if (j < cn) {
            int s[8]; unsigned vv[8];
#pragma unroll
            for (int u = 0; u < 8; ++u) s[u] = __builtin_amdgcn_readlane(sidx, j + u);
#pragma unroll
            for (int u = 0; u < 8; ++u)
                vv[u] = *((const unsigned*)(xlh + (size_t)s[u] * HID) + lane);
#pragma unroll
            for (int u = 0; u < 8; ++u) {
                v2f xv;
                xv.x = __uint_as_float(vv[u] << 16);
                xv.y = __uint_as_float(vv[u] & 0xffff0000u);
                v2f t2 = xv + xrn2;
                v2f e2 = __builtin_elementwise_max(t2, t2 * 0.2f);
                v2f p2 = e2 * a2;
                const float q = dpp8_sum(p2.x + p2.y);
                if (j + u < cn) {
                    const float w = __expf(q);
                    den += w;
                    acc2 += w * xv;
                }
            }
        }
        // overflow edges (rare): broadcast one at a time
        for (int k = 0; k < cov; ++k) {
            int s = (int)ov[(size_t)n * OVS + k];
            if ((unsigned)s >= NN) s = 0;
            const unsigned vvv = *((const unsigned*)(xlh + (size_t)s * HID) + lane);
            v2f xv;
            xv.x = __uint_as_float(vvv << 16);
            xv.y = __uint_as_float(vvv & 0xffff0000u);
            v2f t2 = xv + xrn2;
            v2f e2 = __builtin_elementwise_max(t2, t2 * 0.2f);
            v2f p2 = e2 * a2;
            const float q = dpp8_sum(p2.x + p2.y);
            const float w = __expf(q);
            den += w;
            acc2 += w * xv;
        }

        const unsigned vvs = *((const unsigned*)(xresh + (size_t)n * HID) + lane);
        v2f xrs2;
        xrs2.x = __uint_as_float(vvs << 16);
        xrs2.y = __uint_as_float(vvs & 0xffff0000u);
        const float inv = 1.f / den;
        v2f t = acc2 * inv + xrs2 + b2;
        float2 st; st.x = t.x; st.y = t.y;
        *(float2*)(hfeat + (size_t)n * HID + c0) = st;
    }
}

// ---- Fused tail: per-graph {Wlin+ELU pool} + MLP ---------------------------
__global__ __launch_bounds__(256) void k_tail(
    const float* __restrict__ hfeat, const int* __restrict__ batch,
    const float* __restrict__ Wlin, const float* __restrict__ blin,
    const float* __restrict__ W1, const float* __restrict__ b1,
    const float* __restrict__ W2, const float* __restrict__ b2,
    const float* __restrict__ W3, const float* __restrict__ b3,
    float* __restrict__ out)
{
    __shared__ float sWlin[HID * 16];
    __shared__ float sblin[16];
    __shared__ float sW1[256], sb1[16], sW2[512], sb2[32], sW3[160], sb3[5];
    __shared__ float red[256][17];
    __shared__ float sg[16], sv1[16], sv2[32];
    const int g = blockIdx.x;
    const int tid = threadIdx.x;

    for (int i = tid; i < HID * 16; i += 256) sWlin[i] = Wlin[i];
    if (tid < 16)  sblin[tid] = blin[tid];
    if (tid < 256) sW1[tid] = W1[tid];
    for (int i = tid; i < 512; i += 256) sW2[i] = W2[i];
    if (tid < 160) sW3[tid] = W3[tid];
    if (tid < 16)  sb1[tid] = b1[tid];
    if (tid < 32)  sb2[tid] = b2[tid];
    if (tid < 5)   sb3[tid] = b3[tid];
    __syncthreads();

    int lo = 0, hi = NN;
    while (lo < hi) { int mid = (lo + hi) >> 1; if (batch[mid] < g) lo = mid + 1; else hi = mid; }
    int lo2 = lo, hi2 = NN;
    while (lo2 < hi2) { int mid = (lo2 + hi2) >> 1; if (batch[mid] < g + 1) lo2 = mid + 1; else hi2 = mid; }
    const int nbeg = lo, nend = lo2;

    float sum16[16];
#pragma unroll
    for (int j = 0; j < 16; ++j) sum16[j] = 0.f;

    for (int n = nbeg + tid; n < nend; n += 256) {
        float acc[16];
#pragma unroll
        for (int j = 0; j < 16; ++j) acc[j] = sblin[j];
        const float4* hrow = (const float4*)(hfeat + (size_t)n * HID);
#pragma unroll 8
        for (int kc = 0; kc < 32; ++kc) {
            const float4 v = hrow[kc];
#pragma unroll
            for (int j = 0; j < 16; ++j) {
                acc[j] += v.x * sWlin[(kc * 4 + 0) * 16 + j] + v.y * sWlin[(kc * 4 + 1) * 16 + j]
                        + v.z * sWlin[(kc * 4 + 2) * 16 + j] + v.w * sWlin[(kc * 4 + 3) * 16 + j];
            }
        }
#pragma unroll
        for (int j = 0; j < 16; ++j) {
            float o = acc[j];
            o = o > 0.f ? o : __expf(o) - 1.f;
            sum16[j] += o;
        }
    }

#pragma unroll
    for (int j = 0; j < 16; ++j) red[tid][j] = sum16[j];
    __syncthreads();
    for (int s = 128; s > 0; s >>= 1) {
        if (tid < s) {
#pragma unroll
            for (int j = 0; j < 16; ++j) red[tid][j] += red[tid + s][j];
        }
        __syncthreads();
    }

    if (tid < 16) sg[tid] = red[0][tid] / fmaxf((float)(nend - nbeg), 1.f);
    __syncthreads();
    if (tid < 16) {
        float s = sb1[tid];
#pragma unroll
        for (int c = 0; c < 16; ++c) s += sg[c] * sW1[c * 16 + tid];
        sv1[tid] = fmaxf(s, 0.f);
    }
    __syncthreads();
    if (tid < 32) {
        float s = sb2[tid];
#pragma unroll
        for (int c = 0; c < 16; ++c) s += sv1[c] * sW2[c * 32 + tid];
        sv2[tid] = fmaxf(s, 0.f);
    }
    __syncthreads();
    if (tid < 5) {
        float s = sb3[tid];
#pragma unroll
        for (int c = 0; c < 32; ++c) s += sv2[c] * sW3[c * 5 + tid];
        out[g * 5 + tid] = s;
    }
}

extern "C" void kernel_launch(void* const* d_in, const int* in_sizes, int n_in,
                              void* d_out, int out_size, void* d_ws, size_t ws_size,
                              hipStream_t stream)
{
    const float* x    = (const float*)d_in[0];
    const int*   ei   = (const int*)d_in[1];
    const int*   batch= (const int*)d_in[2];
    const float* Wl   = (const float*)d_in[3];
    const float* bl   = (const float*)d_in[4];
    const float* Wr   = (const float*)d_in[5];
    const float* br   = (const float*)d_in[6];
    const float* att  = (const float*)d_in[7];
    const float* Wres = (const float*)d_in[8];
    const float* bias = (const float*)d_in[9];
    const float* Wlin = (const float*)d_in[10];
    const float* blin = (const float*)d_in[11];
    const float* W1   = (const float*)d_in[12];
    const float* b1   = (const float*)d_in[13];
    const float* W2   = (const float*)d_in[14];
    const float* b2   = (const float*)d_in[15];
    const float* W3   = (const float*)d_in[16];
    const float* b3   = (const float*)d_in[17];
    float* out = (float*)d_out;

    uintptr_t p = (uintptr_t)d_ws;
    unsigned short* xlh   = (unsigned short*)p; p += (size_t)NN * HID * 2;
    unsigned short* xrh   = (unsigned short*)p; p += (size_t)NN * HID * 2;
    unsigned short* xresh = (unsigned short*)p; p += (size_t)NN * HID * 2;
    p = (p + 15) & ~(uintptr_t)15;
    float* hfeat  = (float*)p; p += (size_t)NN * HID * 4;
    int* cnt      = (int*)p;   p += (size_t)(NGRP + 1) * NN * 4;
    unsigned short* col_src = (unsigned short*)p; p += (size_t)NGRP * NN * SLOTG * 2;
    unsigned short* ovp     = (unsigned short*)p; p += (size_t)NN * OVS * 2;

    hipMemsetAsync(cnt, 0, (size_t)(NGRP + 1) * NN * sizeof(int), stream);
    k_work<<<GB2 + SB, 256, 0, stream>>>(x, ei, Wl, bl, Wr, br, Wres,
                                         xlh, xrh, xresh, cnt, col_src, ovp);
    k_agg<<<2048, 256, 0, stream>>>(xlh, xrh, xresh, cnt, col_src, ovp, att, bias, hfeat);
    k_tail<<<NG, 256, 0, stream>>>(hfeat, batch, Wlin, blin,
                                   W1, b1, W2, b2, W3, b3, out);
}

// Round 3
// 215.022 us; speedup vs baseline: 1.0647x; 1.0185x over previous
//
#include <hip/hip_runtime.h>
#include <math.h>

#define NN 50000
#define NE 800000
#define IN_CH 64
#define HEADS 8
#define OC 16
#define HID 128
#define NG 500
#define GB2 ((NN + 63) / 64)        // 782 MFMA-GEMM blocks (64-node tiles)
#define SB 3125                     // scatter blocks: 3125*256 == NE exactly, 1 edge/thread
#define NGRP 8                      // XCD-private CSR groups
#define SLOTG 8                     // slots per node per group (deg/XCD ~ Po(2))
#define OVS 64                      // overflow slots per node (device-scope path)
#define XP 72                       // xb LDS pitch (bf16)
#define WP 72                       // wt LDS pitch (bf16)

typedef float v2f __attribute__((ext_vector_type(2)));
typedef _Float16 h2 __attribute__((ext_vector_type(2)));
typedef __attribute__((ext_vector_type(8))) short frag8;   // 8 bf16 (4 VGPRs)
typedef __attribute__((ext_vector_type(4))) float f32x4;   // MFMA C/D

// round-to-nearest-even f32 -> bf16 (as ushort in low bits) — MFMA input path
__device__ __forceinline__ unsigned bf16rn(float f) {
    unsigned u = __float_as_uint(f);
    return (u + 0x7fffu + ((u >> 16) & 1u)) >> 16;
}

// Sum across the 8-lane head group using DPP (VALU pipe, no LDS).
__device__ __forceinline__ float dpp8_sum(float x) {
    int t;
    t = __builtin_amdgcn_update_dpp(0, __float_as_int(x), 0xB1, 0xF, 0xF, true);  // quad_perm [1,0,3,2]
    x += __int_as_float(t);
    t = __builtin_amdgcn_update_dpp(0, __float_as_int(x), 0x4E, 0xF, 0xF, true);  // quad_perm [2,3,0,1]
    x += __int_as_float(t);
    t = __builtin_amdgcn_update_dpp(0, __float_as_int(x), 0x141, 0xF, 0xF, true); // row_half_mirror
    x += __int_as_float(t);
    return x;
}

// v_dot2_f32_f16: 2-ch dot with f32 accumulate (1 inst). Guarded fallback.
#if __has_builtin(__builtin_amdgcn_fdot2)
#define FDOT2(a, b) __builtin_amdgcn_fdot2((a), (b), 0.0f, false)
#else
__device__ __forceinline__ float FDOT2(h2 a, h2 b) {
    v2f af = __builtin_convertvector(a, v2f);
    v2f bf = __builtin_convertvector(b, v2f);
    return af.x * bf.x + af.y * bf.y;
}
#endif

// R23: per-edge math in packed f16 (pk_add/pk_mul/pk_max + v_dot2_f32_f16).
// pred=false lanes still compute (uniform batch) but don't accumulate.
__device__ __forceinline__ void edge_term(unsigned vv, h2 xrnh, h2 a2h,
                                          float& den, v2f& acc2, bool pred) {
    const h2 xvh = __builtin_bit_cast(h2, vv);
    const h2 t2 = xvh + xrnh;                                   // v_pk_add_f16
    const h2 e2 = __builtin_elementwise_max(t2, t2 * (_Float16)0.2f); // pk_mul+pk_max
    const float q = dpp8_sum(FDOT2(e2, a2h));
    const float w = __expf(q);
    if (pred) {
        den += w;
        const v2f xvf = __builtin_convertvector(xvh, v2f);
        acc2 += w * xvf;                                        // v_pk_fma_f32
    }
}

// ---------------- fused: MFMA GEMM (blocks <GB2) + XCD-private scatter -----
// R22: XCD-private counters+slots via real XCC_ID; workgroup-scope atomic
// stays in this XCD's L2 (no fabric RMW). Overflow -> device-scope spill.
// R23: GEMM outputs stored as fp16 (1-inst cvt epilogue, better precision,
// unlocks packed-f16 math in k_agg). MFMA A/B stay bf16.
__global__ __launch_bounds__(256) void k_work(
    const float* __restrict__ x, const int* __restrict__ ei,
    const float* __restrict__ Wl, const float* __restrict__ bl,
    const float* __restrict__ Wr, const float* __restrict__ br,
    const float* __restrict__ Wres,
    unsigned short* __restrict__ xlh, unsigned short* __restrict__ xrh,
    unsigned short* __restrict__ xresh,
    int* __restrict__ cnt,                 // [NGRP+1][NN]
    unsigned short* __restrict__ col_src,  // [NGRP][NN][SLOTG]
    unsigned short* __restrict__ ov)       // [NN][OVS]
{
    const int tid = threadIdx.x;

    if (blockIdx.x >= GB2) {           // scatter-only block (no barriers)
        const int e = (blockIdx.x - GB2) * 256 + tid;
        if (e < NE) {
            const int s = ei[e];
            const int d = ei[NE + e];
            if ((unsigned)d < NN) {                    // defensive
                int xcc;
                asm volatile("s_getreg_b32 %0, hwreg(HW_REG_XCC_ID)" : "=s"(xcc));
                const int g = xcc & (NGRP - 1);
                const int pos = __hip_atomic_fetch_add(&cnt[(size_t)g * NN + d], 1,
                                                       __ATOMIC_RELAXED,
                                                       __HIP_MEMORY_SCOPE_WORKGROUP);
                if (pos < SLOTG) {
                    col_src[((size_t)g * NN + d) * SLOTG + pos] = (unsigned short)s;
                } else {
                    const int po = atomicAdd(&cnt[(size_t)NGRP * NN + d], 1);  // device scope
                    if (po < OVS)
                        ov[(size_t)d * OVS + po] = (unsigned short)s;
                }
            }
        }
        return;
    }

    __shared__ short xb[64 * XP];      // [node][k] bf16
    __shared__ short wt[128 * WP];     // [col][k] bf16 (W transposed)
    const int n0 = blockIdx.x * 64;

    // stage xb: 64 nodes x 64 k, fp32->bf16
#pragma unroll
    for (int i = 0; i < 4; ++i) {
        const int idx = i * 256 + tid;           // 0..1023 float4s
        const int r = idx >> 4;
        const int j4 = idx & 15;
        float4 v = make_float4(0.f, 0.f, 0.f, 0.f);
        if (n0 + r < NN) v = *(const float4*)(x + (size_t)(n0 + r) * IN_CH + j4 * 4);
        uint2 pk;
        pk.x = bf16rn(v.x) | (bf16rn(v.y) << 16);
        pk.y = bf16rn(v.z) | (bf16rn(v.w) << 16);
        *(uint2*)(xb + r * XP + j4 * 4) = pk;
    }

    const int wv = tid >> 6;           // wave 0..3 -> node subtile
    const int lane = tid & 63;
    const int quad = lane >> 4;
    const int mr = lane & 15;
    const int m0 = wv * 16;

    for (int mtx = 0; mtx < 3; ++mtx) {
        const float* __restrict__ W = (mtx == 0) ? Wl : (mtx == 1) ? Wr : Wres;
        unsigned short* __restrict__ outp = (mtx == 0) ? xlh : (mtx == 1) ? xrh : xresh;

        __syncthreads();   // xb staged (mtx=0) / previous wt consumed (mtx>0)
#pragma unroll
        for (int i = 0; i < 16; ++i) {
            const int idx = i * 256 + tid;       // 0..4095: kp 0..31, c 0..127
            const int kp = idx >> 7;
            const int c = idx & 127;
            const float w0 = W[(2 * kp) * HID + c];
            const float w1 = W[(2 * kp + 1) * HID + c];
            *(unsigned*)(wt + c * WP + 2 * kp) = bf16rn(w0) | (bf16rn(w1) << 16);
        }
        __syncthreads();

        const frag8 a0 = *(const frag8*)(xb + (m0 + mr) * XP + quad * 8);
        const frag8 a1 = *(const frag8*)(xb + (m0 + mr) * XP + 32 + quad * 8);

#pragma unroll
        for (int nt = 0; nt < 8; ++nt) {
            const int c = nt * 16 + mr;          // this lane's global column
            const frag8 b0 = *(const frag8*)(wt + c * WP + quad * 8);
            const frag8 b1 = *(const frag8*)(wt + c * WP + 32 + quad * 8);
            f32x4 acc = {0.f, 0.f, 0.f, 0.f};
            acc = __builtin_amdgcn_mfma_f32_16x16x32_bf16(a0, b0, acc, 0, 0, 0);
            acc = __builtin_amdgcn_mfma_f32_16x16x32_bf16(a1, b1, acc, 0, 0, 0);

            const float bv = (mtx == 0) ? bl[c] : (mtx == 1) ? br[c] : 0.f;
            const int node_base = n0 + m0 + quad * 4;
#pragma unroll
            for (int r = 0; r < 4; ++r) {
                const int node = node_base + r;
                if (node < NN) {
                    const _Float16 hv = (_Float16)(acc[r] + bv);   // v_cvt_f16_f32
                    outp[(size_t)node * HID + c] = __builtin_bit_cast(unsigned short, hv);
                }
            }
        }
    }
}

// ---- Fused attention: single-pass softmax-aggregate, packed-f16 payload ----
// Grouped CSR: lane -> (g = lane>>3, i = lane&7) reads its group slot;
// ballot + ds_permute compacts valid srcs to lanes [0, cn). R23: per-edge
// math in pk-f16 + v_dot2_f32_f16 (~13 VALU/edge vs ~24), and the 8-edge
// batches are software-pipelined (load batch b+1 while computing batch b).
__global__ __launch_bounds__(256) void k_agg(
    const unsigned short* __restrict__ xlh, const unsigned short* __restrict__ xrh,
    const unsigned short* __restrict__ xresh,
    const int* __restrict__ cnt, const unsigned short* __restrict__ col_src,
    const unsigned short* __restrict__ ov,
    const float* __restrict__ att, const float* __restrict__ bias,
    float* __restrict__ hfeat)
{
    const int lane = threadIdx.x & 63;
    const int wid = __builtin_amdgcn_readfirstlane((blockIdx.x * blockDim.x + threadIdx.x) >> 6);
    const int nw = (gridDim.x * blockDim.x) >> 6;
    const int c0 = lane * 2;
    const int hh = lane >> 3;
    const int ci = (lane & 7) * 2;
    const int grp = lane >> 3;          // this lane's CSR group
    const int gsl = lane & 7;           // slot within group
    h2 a2h;  a2h.x = (_Float16)att[hh * OC + ci];  a2h.y = (_Float16)att[hh * OC + ci + 1];
    v2f b2;  b2.x = bias[c0];           b2.y = bias[c0 + 1];

    for (int n = wid; n < NN; n += nw) {
        int cg = cnt[(size_t)grp * NN + n];
        cg = min(max(cg, 0), SLOTG);                      // defensive
        int cov = cnt[(size_t)NGRP * NN + n];
        cov = min(max(cov, 0), OVS);
        const bool valid = gsl < cg;
        const unsigned long long mv = __ballot(valid);
        const int cn = __popcll(mv);
        int slot_s = 0;
        if (valid) slot_s = (int)col_src[((size_t)grp * NN + n) * SLOTG + gsl];
        // compact valid srcs to lanes [0, cn): unique destinations
        const int pv = __popcll(mv & ((1ull << lane) - 1ull));
        const int dst = valid ? pv : (cn + (lane - pv));
        int sidx = __builtin_amdgcn_ds_permute(dst << 2, slot_s);
        if ((unsigned)sidx >= NN) sidx = 0;               // bound all gathers

        const unsigned vvr = *((const unsigned*)(xrh + (size_t)n * HID) + lane);
        const unsigned vvn = *((const unsigned*)(xlh + (size_t)n * HID) + lane);
        const h2 xrnh = __builtin_bit_cast(h2, vvr);
        const h2 xlnh = __builtin_bit_cast(h2, vvn);

        // self-loop term
        const h2 s2 = xlnh + xrnh;
        const h2 l2 = __builtin_elementwise_max(s2, s2 * (_Float16)0.2f);
        const float qs = dpp8_sum(FDOT2(l2, a2h));
        float den = __expf(qs);
        v2f acc2 = den * __builtin_convertvector(xlnh, v2f);

        const int nfull = cn >> 3;      // wave-uniform
        unsigned vvA[8], vvB[8];
        int b = 0;
        if (nfull > 0) {
#pragma unroll
            for (int u = 0; u < 8; ++u) {
                const int s = __builtin_amdgcn_readlane(sidx, u);
                vvA[u] = *((const unsigned*)(xlh + (size_t)s * HID) + lane);
            }
        }
        for (; b + 2 <= nfull; b += 2) {
#pragma unroll
            for (int u = 0; u < 8; ++u) {      // prefetch batch b+1
                const int s = __builtin_amdgcn_readlane(sidx, (b + 1) * 8 + u);
                vvB[u] = *((const unsigned*)(xlh + (size_t)s * HID) + lane);
            }
#pragma unroll
            for (int u = 0; u < 8; ++u) edge_term(vvA[u], xrnh, a2h, den, acc2, true);
            if (b + 2 < nfull) {
#pragma unroll
                for (int u = 0; u < 8; ++u) {  // prefetch batch b+2
                    const int s = __builtin_amdgcn_readlane(sidx, (b + 2) * 8 + u);
                    vvA[u] = *((const unsigned*)(xlh + (size_t)s * HID) + lane);
                }
            }
#pragma unroll
            for (int u = 0; u < 8; ++u) edge_term(vvB[u], xrnh, a2h, den, acc2, true);
        }
        if (b < nfull) {                       // odd final full batch (already loaded)
#pragma unroll
            for (int u = 0; u < 8; ++u) edge_term(vvA[u], xrnh, a2h, den, acc2, true);
        }
        const int j = nfull * 8;
        if (j < cn) {                          // predicated tail batch
#pragma unroll
            for (int u = 0; u < 8; ++u) {
                const int s = __builtin_amdgcn_readlane(sidx, j + u);
                vvA[u] = *((const unsigned*)(xlh + (size_t)s * HID) + lane);
            }
#pragma unroll
            for (int u = 0; u < 8; ++u) edge_term(vvA[u], xrnh, a2h, den, acc2, j + u < cn);
        }
        // overflow edges (rare): broadcast one at a time
        for (int k = 0; k < cov; ++k) {
            int s = (int)ov[(size_t)n * OVS + k];
            if ((unsigned)s >= NN) s = 0;
            const unsigned vvv = *((const unsigned*)(xlh + (size_t)s * HID) + lane);
            edge_term(vvv, xrnh, a2h, den, acc2, true);
        }

        const unsigned vvs = *((const unsigned*)(xresh + (size_t)n * HID) + lane);
        const v2f xrs2 = __builtin_convertvector(__builtin_bit_cast(h2, vvs), v2f);
        const float inv = 1.f / den;
        v2f t = acc2 * inv + xrs2 + b2;
        float2 st; st.x = t.x; st.y = t.y;
        *(float2*)(hfeat + (size_t)n * HID + c0) = st;
    }
}

// ---- Fused tail: per-graph {Wlin+ELU pool} + MLP ---------------------------
__global__ __launch_bounds__(256) void k_tail(
    const float* __restrict__ hfeat, const int* __restrict__ batch,
    const float* __restrict__ Wlin, const float* __restrict__ blin,
    const float* __restrict__ W1, const float* __restrict__ b1,
    const float* __restrict__ W2, const float* __restrict__ b2,
    const float* __restrict__ W3, const float* __restrict__ b3,
    float* __restrict__ out)
{
    __shared__ float sWlin[HID * 16];
    __shared__ float sblin[16];
    __shared__ float sW1[256], sb1[16], sW2[512], sb2[32], sW3[160], sb3[5];
    __shared__ float red[256][17];
    __shared__ float sg[16], sv1[16], sv2[32];
    const int g = blockIdx.x;
    const int tid = threadIdx.x;

    for (int i = tid; i < HID * 16; i += 256) sWlin[i] = Wlin[i];
    if (tid < 16)  sblin[tid] = blin[tid];
    if (tid < 256) sW1[tid] = W1[tid];
    for (int i = tid; i < 512; i += 256) sW2[i] = W2[i];
    if (tid < 160) sW3[tid] = W3[tid];
    if (tid < 16)  sb1[tid] = b1[tid];
    if (tid < 32)  sb2[tid] = b2[tid];
    if (tid < 5)   sb3[tid] = b3[tid];
    __syncthreads();

    int lo = 0, hi = NN;
    while (lo < hi) { int mid = (lo + hi) >> 1; if (batch[mid] < g) lo = mid + 1; else hi = mid; }
    int lo2 = lo, hi2 = NN;
    while (lo2 < hi2) { int mid = (lo2 + hi2) >> 1; if (batch[mid] < g + 1) lo2 = mid + 1; else hi2 = mid; }
    const int nbeg = lo, nend = lo2;

    float sum16[16];
#pragma unroll
    for (int j = 0; j < 16; ++j) sum16[j] = 0.f;

    for (int n = nbeg + tid; n < nend; n += 256) {
        float acc[16];
#pragma unroll
        for (int j = 0; j < 16; ++j) acc[j] = sblin[j];
        const float4* hrow = (const float4*)(hfeat + (size_t)n * HID);
#pragma unroll 8
        for (int kc = 0; kc < 32; ++kc) {
            const float4 v = hrow[kc];
#pragma unroll
            for (int j = 0; j < 16; ++j) {
                acc[j] += v.x * sWlin[(kc * 4 + 0) * 16 + j] + v.y * sWlin[(kc * 4 + 1) * 16 + j]
                        + v.z * sWlin[(kc * 4 + 2) * 16 + j] + v.w * sWlin[(kc * 4 + 3) * 16 + j];
            }
        }
#pragma unroll
        for (int j = 0; j < 16; ++j) {
            float o = acc[j];
            o = o > 0.f ? o : __expf(o) - 1.f;
            sum16[j] += o;
        }
    }

#pragma unroll
    for (int j = 0; j < 16; ++j) red[tid][j] = sum16[j];
    __syncthreads();
    for (int s = 128; s > 0; s >>= 1) {
        if (tid < s) {
#pragma unroll
            for (int j = 0; j < 16; ++j) red[tid][j] += red[tid + s][j];
        }
        __syncthreads();
    }

    if (tid < 16) sg[tid] = red[0][tid] / fmaxf((float)(nend - nbeg), 1.f);
    __syncthreads();
    if (tid < 16) {
        float s = sb1[tid];
#pragma unroll
        for (int c = 0; c < 16; ++c) s += sg[c] * sW1[c * 16 + tid];
        sv1[tid] = fmaxf(s, 0.f);
    }
    __syncthreads();
    if (tid < 32) {
        float s = sb2[tid];
#pragma unroll
        for (int c = 0; c < 16; ++c) s += sv1[c] * sW2[c * 32 + tid];
        sv2[tid] = fmaxf(s, 0.f);
    }
    __syncthreads();
    if (tid < 5) {
        float s = sb3[tid];
#pragma unroll
        for (int c = 0; c < 32; ++c) s += sv2[c] * sW3[c * 5 + tid];
        out[g * 5 + tid] = s;
    }
}

extern "C" void kernel_launch(void* const* d_in, const int* in_sizes, int n_in,
                              void* d_out, int out_size, void* d_ws, size_t ws_size,
                              hipStream_t stream)
{
    const float* x    = (const float*)d_in[0];
    const int*   ei   = (const int*)d_in[1];
    const int*   batch= (const int*)d_in[2];
    const float* Wl   = (const float*)d_in[3];
    const float* bl   = (const float*)d_in[4];
    const float* Wr   = (const float*)d_in[5];
    const float* br   = (const float*)d_in[6];
    const float* att  = (const float*)d_in[7];
    const float* Wres = (const float*)d_in[8];
    const float* bias = (const float*)d_in[9];
    const float* Wlin = (const float*)d_in[10];
    const float* blin = (const float*)d_in[11];
    const float* W1   = (const float*)d_in[12];
    const float* b1   = (const float*)d_in[13];
    const float* W2   = (const float*)d_in[14];
    const float* b2   = (const float*)d_in[15];
    const float* W3   = (const float*)d_in[16];
    const float* b3   = (const float*)d_in[17];
    float* out = (float*)d_out;

    uintptr_t p = (uintptr_t)d_ws;
    unsigned short* xlh   = (unsigned short*)p; p += (size_t)NN * HID * 2;
    unsigned short* xrh   = (unsigned short*)p; p += (size_t)NN * HID * 2;
    unsigned short* xresh = (unsigned short*)p; p += (size_t)NN * HID * 2;
    p = (p + 15) & ~(uintptr_t)15;
    float* hfeat  = (float*)p; p += (size_t)NN * HID * 4;
    int* cnt      = (int*)p;   p += (size_t)(NGRP + 1) * NN * 4;
    unsigned short* col_src = (unsigned short*)p; p += (size_t)NGRP * NN * SLOTG * 2;
    unsigned short* ovp     = (unsigned short*)p; p += (size_t)NN * OVS * 2;

    hipMemsetAsync(cnt, 0, (size_t)(NGRP + 1) * NN * sizeof(int), stream);
    k_work<<<GB2 + SB, 256, 0, stream>>>(x, ei, Wl, bl, Wr, br, Wres,
                                         xlh, xrh, xresh, cnt, col_src, ovp);
    k_agg<<<2048, 256, 0, stream>>>(xlh, xrh, xresh, cnt, col_src, ovp, att, bias, hfeat);
    k_tail<<<NG, 256, 0, stream>>>(hfeat, batch, Wlin, blin,
                                   W1, b1, W2, b2, W3, b3, out);
}